// Round 5
// baseline (148.699 us; speedup 1.0000x reference)
//
#include <hip/hip_runtime.h>
#include <hip/hip_bf16.h>

// PositionalBias: pbv[n,j,h,d] = sum_{l=1..2046} w[h,|j-l|] * v[n,l,h,d]  (j in 1..2046, else 0)
//                 z_pb[l,h]    = sum_{j=1..2046} w[h,|l-j|]               (l in 1..2046, else 0)
// B=4, S=2048, H=12, D=64. Outputs fp32: pbv (6291456) then z_pb (24576).

typedef short short8 __attribute__((ext_vector_type(8)));    // 8 x bf16 bits (4 VGPRs)
typedef float floatx16 __attribute__((ext_vector_type(16))); // 32x32 MFMA accumulator

#define TL 2280   // table len per copy; dword stride 1140 % 32 = 20 -> copies spread over banks

__device__ __forceinline__ unsigned short f2bf(float f) {
  union { __hip_bfloat16 b; unsigned short u; } cv;
  cv.b = __float2bfloat16(f);  // RNE
  return cv.u;
}

// ---------------- prep: v transpose (+ zpb in extra blocks) -------------------------------------
__global__ __launch_bounds__(256) void prep_kernel(const float* __restrict__ v,
                                                   const float* __restrict__ w,
                                                   unsigned short* __restrict__ vb,
                                                   float* __restrict__ zout) {
  __shared__ float smem[64 * 65];
  const int lt = blockIdx.x;   // 0..32; 32 => zpb block
  const int h  = blockIdx.y;   // 12
  const int n  = blockIdx.z;   // 4
  const int tid = threadIdx.x;

  if (lt == 32) {               // ---- zpb: z[i+1] = P[i] + P[2045-i] - w[h,0] ----
    if (n != 0) return;
    float* wv  = smem;          // [2048]
    float* pfx = smem + 2048;   // [2048]
    __shared__ float wsum[4];
    const float* wh = w + (size_t)h * 2048;
    for (int i = tid; i < 2048; i += 256) wv[i] = (i < 2046) ? wh[i] : 0.f;
    __syncthreads();
    const int base = tid * 8;
    float run0 = 0.f;
    #pragma unroll
    for (int k = 0; k < 8; ++k) run0 += wv[base + k];
    float x = run0;
    #pragma unroll
    for (int d = 1; d < 64; d <<= 1) {
      float y = __shfl_up(x, d);
      if ((tid & 63) >= d) x += y;
    }
    if ((tid & 63) == 63) wsum[tid >> 6] = x;
    __syncthreads();
    const int wid = tid >> 6;
    float woff = 0.f;
    #pragma unroll
    for (int u = 0; u < 3; ++u) { float t = wsum[u]; if (u < wid) woff += t; }
    float pr = x + woff - run0;
    #pragma unroll
    for (int k = 0; k < 8; ++k) { pr += wv[base + k]; pfx[base + k] = pr; }
    __syncthreads();
    for (int i = tid; i < 2046; i += 256) {
      float z = pfx[i] + pfx[2045 - i] - wv[0];
      zout[(size_t)(i + 1) * 12 + h] = z;
    }
    if (tid == 0) { zout[h] = 0.f; zout[(size_t)2047 * 12 + h] = 0.f; }
    return;
  }

  // ---- transpose tile: 64 l x 64 d ----
  float (*tile)[65] = (float(*)[65])smem;
  const int l0 = lt * 64;
  {
    const int row = tid >> 2;          // 0..63 (l within tile)
    const int cq  = (tid & 3) * 16;    // 4 float4 per thread
    const float* src = v + (((size_t)n * 2048 + (l0 + row)) * 12 + h) * 64 + cq;
    #pragma unroll
    for (int u = 0; u < 4; ++u) {
      float4 f4 = *(const float4*)(src + u * 4);
      tile[row][cq + u * 4 + 0] = f4.x;
      tile[row][cq + u * 4 + 1] = f4.y;
      tile[row][cq + u * 4 + 2] = f4.z;
      tile[row][cq + u * 4 + 3] = f4.w;
    }
  }
  __syncthreads();
  {
    const int d = tid >> 2;            // 0..63
    const int q = tid & 3;             // 0..3 (16 l each)
    const int nd = n * 64 + d;
    unsigned short buf[16] __attribute__((aligned(16)));
    #pragma unroll
    for (int jj = 0; jj < 16; ++jj) {
      int l = l0 + q * 16 + jj;
      float f = tile[q * 16 + jj][d];
      buf[jj] = (l == 0 || l == 2047) ? (unsigned short)0 : f2bf(f);
    }
    unsigned short* dst = vb + ((size_t)h * 256 + nd) * 2048 + l0 + q * 16;
    *(uint4*)dst       = *(const uint4*)&buf[0];
    *(uint4*)(dst + 8) = *(const uint4*)&buf[8];
  }
}

// ---------------- main Toeplitz GEMM: 32x32x16 MFMA, barrier-free K-loop ------------------------
// Block = 128j x 64nd; 4 waves each own a PRIVATE 64j x 32nd strip (wm = j-half, wn = nd-half).
// Per 64-k iter per wave: 8 MFMA (2 j-tiles x 4 k-phases), 6 distinct A-frags (Toeplitz collapses
// (mt=1,p) == (mt=0,p-2)), 4 fresh A ds_read_b128, 4 B global b128 pipelined 2 iters deep.
// A layout (32x32x16): m = lane&31, k = (lane>>5)*8 + i.  B: n = lane&31, k = (lane>>5)*8 + i.
// C/D [m74/m101]: col = lane&31, row = (reg&3) + 8*(reg>>2) + 4*(lane>>5).
__global__ __launch_bounds__(256, 3) void gemm_kernel(const float* __restrict__ w,
                                                      const unsigned short* __restrict__ vb,
                                                      float* __restrict__ out) {
  __shared__ __attribute__((aligned(16))) short Tls[8 * TL];  // 36.5 KB

  const int ndt = blockIdx.x & 3;
  const int h   = blockIdx.x >> 2;    // 12
  const int jt  = blockIdx.y;         // 16
  const int tid = threadIdx.x;
  const int lane = tid & 63;
  const int wid  = tid >> 6;
  const int wm = wid >> 1, wn = wid & 1;
  const int ln31 = lane & 31, half = lane >> 5;
  const int jb = jt * 128;
  const int jw = jb + wm * 64;
  const int strip = ndt * 64 + wn * 32;    // wave's private 32-nd strip

  // B row pointer: nd = strip + ln31, k base = half*8
  const unsigned short* brow = vb + ((size_t)h * 256 + strip + ln31) * 2048 + half * 8;

  // issue t=0 and t=1 B loads before the table build (latency hidden under build)
  short8 B0[4], B1[4];
  #pragma unroll
  for (int p = 0; p < 4; ++p) B0[p] = *(const short8*)(brow + p * 16);
  #pragma unroll
  for (int p = 0; p < 4; ++p) B1[p] = *(const short8*)(brow + 64 + p * 16);

  // build reversed, 8x-shifted kernel table: T_c[p'] = w_ext[127 + jb - p' - c]
  const float* wh = w + (size_t)h * 2048;
  for (int g = tid; g < 8 * (TL / 8); g += 256) {
    int c  = g / (TL / 8);
    int p8 = (g - c * (TL / 8)) * 8;
    unsigned short buf[8] __attribute__((aligned(16)));
    #pragma unroll
    for (int i = 0; i < 8; ++i) {
      int t = 127 + jb - (p8 + i) - c;
      int a = t < 0 ? -t : t;
      buf[i] = (a <= 2045) ? f2bf(wh[a]) : (unsigned short)0;
    }
    *(short8*)&Tls[c * TL + p8] = *(const short8*)buf;
  }
  __syncthreads();   // the only block-wide sync

  // A-frag: value[i] = w_ext[j - k], j = jw + mt*32 + ln31, k = l0 + p*16 + half*8 + i
  // p0 = l0 + (p - 2*mt)*16 + pbase; aligned b128 from shifted copy c = p0 & 7.
  const int pbase = 127 + half * 8 - wm * 64 - ln31;
  auto load_af = [&](int p0) -> short8 {
    int c = p0 & 7;
    return *(const short8*)&Tls[c * TL + (p0 - c)];
  };

  // afr[i] holds diagonal offset (i-2)*16 relative to current l0; current iter uses afr[0..5]
  short8 afr[6];
  #pragma unroll
  for (int i = 0; i < 6; ++i) afr[i] = load_af((i - 2) * 16 + pbase);

  floatx16 acc0 = {0.f}, acc1 = {0.f};
  #pragma unroll
  for (int e = 0; e < 16; ++e) { acc0[e] = 0.f; acc1[e] = 0.f; }

  #pragma unroll 2
  for (int t = 0; t < 32; ++t) {
    const int l0 = t * 64;
    // B prefetch distance 2 (tail clamp re-reads t=31: harmless)
    const int tn = (t < 30) ? t + 2 : 31;
    short8 Bn[4];
    #pragma unroll
    for (int p = 0; p < 4; ++p) Bn[p] = *(const short8*)(brow + tn * 64 + p * 16);
    // A prefetch distance 1: next iter's afr[2..5]  (p0 <= 2048+48+135+... < TL: in-bounds)
    short8 na[4];
    #pragma unroll
    for (int q = 0; q < 4; ++q) na[q] = load_af(l0 + 64 + q * 16 + pbase);

    // 8 MFMAs: mt=0 uses afr[p+2], mt=1 uses afr[p]; two independent acc chains interleaved
    #pragma unroll
    for (int p = 0; p < 4; ++p) {
      acc0 = __builtin_amdgcn_mfma_f32_32x32x16_bf16(afr[p + 2], B0[p], acc0, 0, 0, 0);
      acc1 = __builtin_amdgcn_mfma_f32_32x32x16_bf16(afr[p],     B0[p], acc1, 0, 0, 0);
    }

    // slide window by 4 diagonals; rotate B pipeline
    afr[0] = afr[4]; afr[1] = afr[5];
    #pragma unroll
    for (int q = 0; q < 4; ++q) { afr[q + 2] = na[q]; B0[q] = B1[q]; B1[q] = Bn[q]; }
  }

  // epilogue: col = ln31 (nd), row = (r&3) + 8*(r>>2) + 4*half (j within 32-tile)
  const int ndv = strip + ln31;
  const int n = ndv >> 6, d = ndv & 63;
  float* obase = out + (size_t)n * 1572864 + (size_t)h * 64 + d;
  #pragma unroll
  for (int mt = 0; mt < 2; ++mt) {
    const floatx16 a = mt ? acc1 : acc0;
    const int jt32 = jw + mt * 32 + 4 * half;
    #pragma unroll
    for (int r = 0; r < 16; ++r) {
      int j = jt32 + (r & 3) + 8 * (r >> 2);
      float val = (j == 0 || j == 2047) ? 0.f : a[r];
      obase[(size_t)j * 768] = val;
    }
  }
}

extern "C" void kernel_launch(void* const* d_in, const int* in_sizes, int n_in,
                              void* d_out, int out_size, void* d_ws, size_t ws_size,
                              hipStream_t stream) {
  const float* v = (const float*)d_in[0];   // (4,2048,12,64) fp32
  const float* w = (const float*)d_in[1];   // (12,2048) fp32
  float* out = (float*)d_out;               // pbv (6291456) + z_pb (24576) fp32
  unsigned short* vb = (unsigned short*)d_ws;  // 12*256*2048 bf16 = 12.58 MB

  prep_kernel<<<dim3(33, 12, 4), 256, 0, stream>>>(v, w, vb, out + 6291456);
  gemm_kernel<<<dim3(48, 16, 1), 256, 0, stream>>>(w, vb, out);
}

// Round 6
// 127.836 us; speedup vs baseline: 1.1632x; 1.1632x over previous
//
#include <hip/hip_runtime.h>
#include <hip/hip_bf16.h>

// PositionalBias: pbv[n,j,h,d] = sum_{l=1..2046} w[h,|j-l|] * v[n,l,h,d]  (j in 1..2046, else 0)
//                 z_pb[l,h]    = sum_{j=1..2046} w[h,|l-j|]               (l in 1..2046, else 0)
// B=4, S=2048, H=12, D=64. Outputs fp32: pbv (6291456) then z_pb (24576).

typedef short short8 __attribute__((ext_vector_type(8)));   // 8 x bf16 bits (4 VGPRs)
typedef float floatx4 __attribute__((ext_vector_type(4)));  // MFMA accumulator

#define TW 4336        // A-table window per shifted copy (shorts); tab[h][c][p] = w_ext[2160-p-c]
#define VB_ELEMS 6291456  // 12*256*2048

__device__ __forceinline__ unsigned short f2bf(float f) {
  union { __hip_bfloat16 b; unsigned short u; } cv;
  cv.b = __float2bfloat16(f);  // RNE
  return cv.u;
}

// ---------------- prep: v transpose + zpb + global A-table build --------------------------------
__global__ __launch_bounds__(256) void prep_kernel(const float* __restrict__ v,
                                                   const float* __restrict__ w,
                                                   unsigned short* __restrict__ vb,
                                                   unsigned short* __restrict__ tab,
                                                   float* __restrict__ zout) {
  __shared__ float smem[64 * 65];
  const int lt = blockIdx.x;   // 0..32; 32 => service block (zpb + tab)
  const int h  = blockIdx.y;   // 12
  const int n  = blockIdx.z;   // 4
  const int tid = threadIdx.x;

  if (lt == 32) {
    // ---- A-table: this (h,n) block builds copies c = 2n, 2n+1 ----
    const float* wh = w + (size_t)h * 2048;
    unsigned short* tabh = tab + (size_t)h * 8 * TW;
    #pragma unroll
    for (int cc = 0; cc < 2; ++cc) {
      const int c = 2 * n + cc;
      for (int p = tid; p < TW; p += 256) {
        int t = 2160 - p - c;
        int a = t < 0 ? -t : t;
        tabh[(size_t)c * TW + p] = (a <= 2045) ? f2bf(wh[a]) : (unsigned short)0;
      }
    }
    if (n != 0) return;

    // ---- zpb: z[i+1] = P[i] + P[2045-i] - w[h,0] ----
    float* wv  = smem;          // [2048]
    float* pfx = smem + 2048;   // [2048]
    __shared__ float wsum[4];
    for (int i = tid; i < 2048; i += 256) wv[i] = (i < 2046) ? wh[i] : 0.f;
    __syncthreads();
    const int base = tid * 8;
    float run0 = 0.f;
    #pragma unroll
    for (int k = 0; k < 8; ++k) run0 += wv[base + k];
    float x = run0;
    #pragma unroll
    for (int d = 1; d < 64; d <<= 1) {
      float y = __shfl_up(x, d);
      if ((tid & 63) >= d) x += y;
    }
    if ((tid & 63) == 63) wsum[tid >> 6] = x;
    __syncthreads();
    const int wid = tid >> 6;
    float woff = 0.f;
    #pragma unroll
    for (int u = 0; u < 3; ++u) { float t = wsum[u]; if (u < wid) woff += t; }
    float pr = x + woff - run0;
    #pragma unroll
    for (int k = 0; k < 8; ++k) { pr += wv[base + k]; pfx[base + k] = pr; }
    __syncthreads();
    for (int i = tid; i < 2046; i += 256) {
      float z = pfx[i] + pfx[2045 - i] - wv[0];
      zout[(size_t)(i + 1) * 12 + h] = z;
    }
    if (tid == 0) { zout[h] = 0.f; zout[(size_t)2047 * 12 + h] = 0.f; }
    return;
  }

  // ---- transpose tile: 64 l x 64 d -> vb[h][nd][l] bf16, zero l=0,2047 ----
  float (*tile)[65] = (float(*)[65])smem;
  const int l0 = lt * 64;
  {
    const int row = tid >> 2;          // 0..63 (l within tile)
    const int cq  = (tid & 3) * 16;    // 4 float4 per thread
    const float* src = v + (((size_t)n * 2048 + (l0 + row)) * 12 + h) * 64 + cq;
    #pragma unroll
    for (int u = 0; u < 4; ++u) {
      float4 f4 = *(const float4*)(src + u * 4);
      tile[row][cq + u * 4 + 0] = f4.x;
      tile[row][cq + u * 4 + 1] = f4.y;
      tile[row][cq + u * 4 + 2] = f4.z;
      tile[row][cq + u * 4 + 3] = f4.w;
    }
  }
  __syncthreads();
  {
    const int d = tid >> 2;            // 0..63
    const int q = tid & 3;             // 0..3 (16 l each)
    const int nd = n * 64 + d;
    unsigned short buf[16] __attribute__((aligned(16)));
    #pragma unroll
    for (int jj = 0; jj < 16; ++jj) {
      int l = l0 + q * 16 + jj;
      float f = tile[q * 16 + jj][d];
      buf[jj] = (l == 0 || l == 2047) ? (unsigned short)0 : f2bf(f);
    }
    unsigned short* dst = vb + ((size_t)h * 256 + nd) * 2048 + l0 + q * 16;
    *(uint4*)dst       = *(const uint4*)&buf[0];
    *(uint4*)(dst + 8) = *(const uint4*)&buf[8];
  }
}

// ---------------- main Toeplitz GEMM: ZERO-LDS, all operands from global ------------------------
// Block = 128j x 64nd, 4 waves each own a private 128j x 16nd strip. No LDS, no barrier,
// no prologue: A-frags are single global_load_dwordx4 from the precomputed shifted table
// (lane's copy index c = (-lm)&7 and alignment are loop-invariant); B-frags are per-lane
// 16B loads from vb. Both L2-resident. B pipelined distance-2, A distance-1.
// Grid (48=(h,ndt), 16=jt): 48%8==0 -> all 16 jt blocks of a (h,ndt) slice on one XCD.
__global__ __launch_bounds__(256, 4) void gemm_kernel(const unsigned short* __restrict__ vb,
                                                      const unsigned short* __restrict__ tab,
                                                      float* __restrict__ out) {
  const int ndt = blockIdx.x & 3;
  const int h   = blockIdx.x >> 2;    // 12
  const int jt  = blockIdx.y;         // 16
  const int lane = threadIdx.x & 63;
  const int wid  = threadIdx.x >> 6;
  const int lm = lane & 15, quad = lane >> 4;
  const int jb = jt * 128;
  const int strip = ndt * 64 + wid * 16;   // wave's private 16-nd strip

  // B: lane reads row nd = strip+lm at k = t*64 + kc*32 + quad*8 + i
  const unsigned short* brow = vb + ((size_t)h * 256 + strip + lm) * 2048 + quad * 8;

  // A: value[i] = w_ext[(jb+lm) + 16*ma - (l0 + kc*32 + quad*8) - i]
  //    = tab[h][c][ab_off + l0 + 16*g],  g = 2*kc - ma;  c = (-lm)&7 (loop-invariant, 16B-aligned)
  const int c = (-lm) & 7;
  const unsigned short* ab = tab + (size_t)h * 8 * TW + (size_t)c * TW
                                 + (2160 - (jb + lm) - c) + quad * 8;
  auto A = [&](int off) -> short8 { return *(const short8*)(ab + off); };

  // kick off the deepest-latency loads first (cold L2 on first touch)
  short8 bc0 = *(const short8*)(brow);             // t=0, kc=0
  short8 bc1 = *(const short8*)(brow + 32);        // t=0, kc=1
  short8 bn0 = *(const short8*)(brow + 64);        // t=1
  short8 bn1 = *(const short8*)(brow + 96);

  short8 afr[10];                      // afr[i] = diagonal g = i-7 relative to current l0
  #pragma unroll
  for (int i = 0; i < 10; ++i) afr[i] = A((i - 7) * 16);

  floatx4 acc[8];
  #pragma unroll
  for (int ma = 0; ma < 8; ++ma) acc[ma] = (floatx4){0.f, 0.f, 0.f, 0.f};

  #pragma unroll 4
  for (int t = 0; t < 32; ++t) {
    const int l0 = t * 64;
    // B prefetch distance 2 (tail clamp re-reads 31: harmless, in-bounds)
    const int t2 = (t < 30) ? t + 2 : 31;
    short8 b20 = *(const short8*)(brow + t2 * 64);
    short8 b21 = *(const short8*)(brow + t2 * 64 + 32);
    // A prefetch distance 1: next iter's fresh diagonals g = -1,0,1,2 (in-bounds by TW sizing)
    short8 na0 = A(l0 + 64 - 16);
    short8 na1 = A(l0 + 64);
    short8 na2 = A(l0 + 64 + 16);
    short8 na3 = A(l0 + 64 + 32);

    #pragma unroll
    for (int ma = 0; ma < 8; ++ma)   // kc=0: g = -ma  -> idx 7-ma
      acc[ma] = __builtin_amdgcn_mfma_f32_16x16x32_bf16(afr[7 - ma], bc0, acc[ma], 0, 0, 0);
    #pragma unroll
    for (int ma = 0; ma < 8; ++ma)   // kc=1: g = 2-ma -> idx 9-ma
      acc[ma] = __builtin_amdgcn_mfma_f32_16x16x32_bf16(afr[9 - ma], bc1, acc[ma], 0, 0, 0);

    // slide A window by 4 diagonals; rotate B pipeline (renamed by unroll)
    #pragma unroll
    for (int i = 0; i < 6; ++i) afr[i] = afr[i + 4];
    afr[6] = na0; afr[7] = na1; afr[8] = na2; afr[9] = na3;
    bc0 = bn0; bc1 = bn1; bn0 = b20; bn1 = b21;
  }

  // epilogue: D row = quad*4 + r (j), col = lm (nd); zero rows j=0 and j=2047
  const int ndv = strip + lm;
  const int n = ndv >> 6, d = ndv & 63;
  float* obase = out + (size_t)n * 1572864 + (size_t)h * 64 + d;
  #pragma unroll
  for (int ma = 0; ma < 8; ++ma) {
    floatx4 cc = acc[ma];
    #pragma unroll
    for (int r = 0; r < 4; ++r) {
      int j = jb + ma * 16 + quad * 4 + r;
      float val = (j == 0 || j == 2047) ? 0.f : cc[r];
      obase[(size_t)j * 768] = val;
    }
  }
}

extern "C" void kernel_launch(void* const* d_in, const int* in_sizes, int n_in,
                              void* d_out, int out_size, void* d_ws, size_t ws_size,
                              hipStream_t stream) {
  const float* v = (const float*)d_in[0];   // (4,2048,12,64) fp32
  const float* w = (const float*)d_in[1];   // (12,2048) fp32
  float* out = (float*)d_out;               // pbv (6291456) + z_pb (24576) fp32
  unsigned short* vb  = (unsigned short*)d_ws;      // 12.58 MB
  unsigned short* tab = vb + VB_ELEMS;              // 12*8*TW*2B = 832 KB (ws total 13.4 MB)

  prep_kernel<<<dim3(33, 12, 4), 256, 0, stream>>>(v, w, vb, tab, out + 6291456);
  gemm_kernel<<<dim3(48, 16, 1), 256, 0, stream>>>(vb, tab, out);
}

// Round 7
// 118.679 us; speedup vs baseline: 1.2530x; 1.0772x over previous
//
#include <hip/hip_runtime.h>
#include <hip/hip_bf16.h>

// PositionalBias: pbv[n,j,h,d] = sum_{l=1..2046} w[h,|j-l|] * v[n,l,h,d]  (j in 1..2046, else 0)
//                 z_pb[l,h]    = sum_{j=1..2046} w[h,|l-j|]               (l in 1..2046, else 0)
// B=4, S=2048, H=12, D=64. Outputs fp32: pbv (6291456) then z_pb (24576).
// SINGLE-DISPATCH fused kernel: blocks 0..767 = Toeplitz GEMM (48 slices x 16 j-tiles),
// blocks 768..779 = z_pb. No workspace, no prep pass: B comes straight from v (fp32->bf16
// in registers), A comes from a per-block LDS Toeplitz table (8 pre-shifted copies ->
// one aligned ds_read_b128 per fragment).

typedef short short8 __attribute__((ext_vector_type(8)));   // 8 x bf16 bits (4 VGPRs)
typedef float floatx4 __attribute__((ext_vector_type(4)));  // MFMA accumulator

#define TL 2280   // A-table length per shifted copy (shorts); 8 copies = 36.5 KB LDS

__device__ __forceinline__ unsigned short f2bf(float f) {
  union { __hip_bfloat16 b; unsigned short u; } cv;
  cv.b = __float2bfloat16(f);  // RNE
  return cv.u;
}

__global__ __launch_bounds__(256, 3) void fused_kernel(const float* __restrict__ v,
                                                       const float* __restrict__ w,
                                                       float* __restrict__ out) {
  __shared__ __attribute__((aligned(16))) short Tls[8 * TL];  // 36.5 KB (aliased by zpb)

  const int bx  = blockIdx.x;
  const int tid = threadIdx.x;

  if (bx >= 768) {   // ---------------- zpb: z[i+1] = P[i] + P[2045-i] - w[h,0] ----------------
    const int h = bx - 768;
    float* wv  = (float*)Tls;          // [2048]
    float* pfx = ((float*)Tls) + 2048; // [2048]
    __shared__ float wsum[4];
    const float* wh = w + (size_t)h * 2048;
    float* zout = out + 6291456;
    for (int i = tid; i < 2048; i += 256) wv[i] = (i < 2046) ? wh[i] : 0.f;
    __syncthreads();
    const int base = tid * 8;
    float run0 = 0.f;
    #pragma unroll
    for (int k = 0; k < 8; ++k) run0 += wv[base + k];
    float x = run0;
    #pragma unroll
    for (int dd = 1; dd < 64; dd <<= 1) {
      float y = __shfl_up(x, dd);
      if ((tid & 63) >= dd) x += y;
    }
    if ((tid & 63) == 63) wsum[tid >> 6] = x;
    __syncthreads();
    const int wid4 = tid >> 6;
    float woff = 0.f;
    #pragma unroll
    for (int u = 0; u < 3; ++u) { float t = wsum[u]; if (u < wid4) woff += t; }
    float pr = x + woff - run0;
    #pragma unroll
    for (int k = 0; k < 8; ++k) { pr += wv[base + k]; pfx[base + k] = pr; }
    __syncthreads();
    for (int i = tid; i < 2046; i += 256) {
      float z = pfx[i] + pfx[2045 - i] - wv[0];
      zout[(size_t)(i + 1) * 12 + h] = z;
    }
    if (tid == 0) { zout[h] = 0.f; zout[(size_t)2047 * 12 + h] = 0.f; }
    return;
  }

  // ---------------- GEMM block: 128j x 64nd; 4 waves own private 128j x 16nd strips ------------
  // Same-slice blocks are 48 apart in linear id (48%8==0) -> same XCD -> v-slice L2-resident.
  const int slice = bx % 48;          // (h, ndt)
  const int jt    = bx / 48;          // 16
  const int ndt = slice & 3;          // batch n == ndt for the whole block
  const int h   = slice >> 2;
  const int lane = tid & 63, wid = tid >> 6;
  const int lm = lane & 15, quad = lane >> 4;
  const int jb = jt * 128;
  const int strip = ndt * 64 + wid * 16;
  const int d = (strip + lm) & 63;    // lane's head-dim index

  // B source: v[ndt][l][h][d], stride in l = 768 floats. Per instr: 4 quads x 16 consecutive d
  // = 4 fully-used 64B segments.
  const float* vrow = v + (((size_t)ndt * 2048) * 12 + h) * 64 + d;

  // raw B for t=0,1 issued before the table build (latency hidden under build)
  float r0[16], rA[16];
  {
    const int lb = quad * 8;
    #pragma unroll
    for (int i = 0; i < 8; ++i) r0[i]     = vrow[(size_t)(lb + i) * 768];
    #pragma unroll
    for (int i = 0; i < 8; ++i) r0[8 + i] = vrow[(size_t)(lb + 32 + i) * 768];
    #pragma unroll
    for (int i = 0; i < 8; ++i) rA[i]     = vrow[(size_t)(64 + lb + i) * 768];
    #pragma unroll
    for (int i = 0; i < 8; ++i) rA[8 + i] = vrow[(size_t)(64 + lb + 32 + i) * 768];
  }

  // build reversed, 8x-shifted Toeplitz table: T_c[p] = w_ext[127 + jb - p - c]
  const float* wh = w + (size_t)h * 2048;
  for (int g = tid; g < 8 * (TL / 8); g += 256) {
    int c  = g / (TL / 8);
    int p8 = (g - c * (TL / 8)) * 8;
    unsigned short buf[8] __attribute__((aligned(16)));
    #pragma unroll
    for (int i = 0; i < 8; ++i) {
      int t = 127 + jb - (p8 + i) - c;
      int a = t < 0 ? -t : t;
      buf[i] = (a <= 2045) ? f2bf(wh[a]) : (unsigned short)0;
    }
    *(short8*)&Tls[c * TL + p8] = *(const short8*)buf;
  }
  __syncthreads();   // the only block-wide sync

  // pack raw fp32 -> bf16 B-frags, zeroing the l=0 / l=2047 border columns
  auto packB = [&](int t, const float* f, short8& b0, short8& b1) {
    const int lb = t * 64 + quad * 8;
    #pragma unroll
    for (int i = 0; i < 8; ++i) {
      int la = lb + i, lc = lb + 32 + i;
      b0[i] = (la == 0 || la == 2047) ? (short)0 : (short)f2bf(f[i]);
      b1[i] = (lc == 0 || lc == 2047) ? (short)0 : (short)f2bf(f[8 + i]);
    }
  };

  // A-frag: value[i] = w_ext[j - k], j = jb + ma*16 + lm, k = l0 + kc*32 + quad*8 + i
  // p0 = l0 + 16*g + pbase, g = 2*kc - ma in [-7,2]; aligned b128 from copy (p0 & 7).
  const int pbase = 127 + quad * 8 - lm;
  auto load_af = [&](int p0) -> short8 {
    int c = p0 & 7;
    return *(const short8*)&Tls[c * TL + (p0 - c)];
  };

  short8 afr[10];                      // afr[i] = diagonal g = i-7 relative to current l0
  #pragma unroll
  for (int i = 0; i < 10; ++i) afr[i] = load_af((i - 7) * 16 + pbase);

  short8 bc0, bc1;
  packB(0, r0, bc0, bc1);

  floatx4 acc[8];
  #pragma unroll
  for (int ma = 0; ma < 8; ++ma) acc[ma] = (floatx4){0.f, 0.f, 0.f, 0.f};

  #pragma unroll 4
  for (int t = 0; t < 32; ++t) {
    const int l0 = t * 64;
    // issue raw B loads for t+2 (tail clamp re-reads 31: harmless)
    float rN[16];
    const int lb2 = ((t < 30) ? t + 2 : 31) * 64 + quad * 8;
    #pragma unroll
    for (int i = 0; i < 8; ++i) rN[i]     = vrow[(size_t)(lb2 + i) * 768];
    #pragma unroll
    for (int i = 0; i < 8; ++i) rN[8 + i] = vrow[(size_t)(lb2 + 32 + i) * 768];
    // A prefetch distance 1: next iter's fresh diagonals g = -1,0,1,2
    const int l0n = (t < 31) ? l0 + 64 : l0;
    short8 na0 = load_af(l0n - 16 + pbase);
    short8 na1 = load_af(l0n      + pbase);
    short8 na2 = load_af(l0n + 16 + pbase);
    short8 na3 = load_af(l0n + 32 + pbase);

    #pragma unroll
    for (int ma = 0; ma < 8; ++ma)   // kc=0: g = -ma  -> idx 7-ma
      acc[ma] = __builtin_amdgcn_mfma_f32_16x16x32_bf16(afr[7 - ma], bc0, acc[ma], 0, 0, 0);
    #pragma unroll
    for (int ma = 0; ma < 8; ++ma)   // kc=1: g = 2-ma -> idx 9-ma
      acc[ma] = __builtin_amdgcn_mfma_f32_16x16x32_bf16(afr[9 - ma], bc1, acc[ma], 0, 0, 0);

    // pack rA (raw of t+1, in flight ~2 iterations) -> current B
    packB((t < 31) ? t + 1 : 31, rA, bc0, bc1);

    // slide A window by 4 diagonals; rotate raw-B pipeline
    #pragma unroll
    for (int i = 0; i < 6; ++i) afr[i] = afr[i + 4];
    afr[6] = na0; afr[7] = na1; afr[8] = na2; afr[9] = na3;
    #pragma unroll
    for (int i = 0; i < 16; ++i) rA[i] = rN[i];
  }

  // epilogue: D row = quad*4 + r (j), col = lm (nd); zero rows j=0 and j=2047
  float* obase = out + (size_t)ndt * 1572864 + (size_t)h * 64 + d;
  #pragma unroll
  for (int ma = 0; ma < 8; ++ma) {
    floatx4 cc = acc[ma];
    #pragma unroll
    for (int r = 0; r < 4; ++r) {
      int j = jb + ma * 16 + quad * 4 + r;
      float val = (j == 0 || j == 2047) ? 0.f : cc[r];
      obase[(size_t)j * 768] = val;
    }
  }
}

extern "C" void kernel_launch(void* const* d_in, const int* in_sizes, int n_in,
                              void* d_out, int out_size, void* d_ws, size_t ws_size,
                              hipStream_t stream) {
  const float* v = (const float*)d_in[0];   // (4,2048,12,64) fp32
  const float* w = (const float*)d_in[1];   // (12,2048) fp32
  float* out = (float*)d_out;               // pbv (6291456) + z_pb (24576) fp32
  fused_kernel<<<dim3(780), 256, 0, stream>>>(v, w, out);
}